// Round 5
// baseline (356.762 us; speedup 1.0000x reference)
//
#include <hip/hip_runtime.h>
#include <hip/hip_bf16.h>

// LFQ forward, split into low-pressure single-purpose kernels (MI355X gfx950).
// d_out (f32): out[16384*512], indices[16384] (as float), aux_loss[1]
// ws: xp[16384*12] (768 KB) | P[256*4096] (4 MB) | scal[2] {C_sum, E_sum}

#define NS    16384
#define NOUT  (NS*512)
#define AUXO  (NOUT+NS)
#define INVT2 200.0f

// -------- K_A: projection-in -> xp, indices. 16 lanes/sample, 32 samples/block.
__global__ __launch_bounds__(256, 4) void k_projin(
    const float* __restrict__ x,
    const float* __restrict__ w_in, const float* __restrict__ b_in,
    float* __restrict__ xp, float* __restrict__ idx_out) {
  __shared__ __align__(16) float s_wi[6144];   // w_in row-major [12][512]
  const int t = threadIdx.x;
  #pragma unroll
  for (int k = 0; k < 24; ++k) s_wi[t + k * 256] = w_in[t + k * 256];
  __syncthreads();

  const int sub = t & 15;
  const int grp = t >> 4;   // 0..15
  float bin[12];
  #pragma unroll
  for (int d = 0; d < 12; ++d) bin[d] = b_in[d];

  #pragma unroll 1
  for (int bt = 0; bt < 2; ++bt) {
    const int i = blockIdx.x * 32 + bt * 16 + grp;
    const float* xrow = x + (size_t)i * 512;
    float4 xv[8];
    #pragma unroll
    for (int e4 = 0; e4 < 8; ++e4)
      xv[e4] = *(const float4*)(xrow + e4 * 64 + sub * 4);

    float p[12];
    #pragma unroll
    for (int d = 0; d < 12; ++d) p[d] = 0.f;
    #pragma unroll
    for (int e4 = 0; e4 < 8; ++e4) {
      #pragma unroll
      for (int d = 0; d < 12; ++d) {
        float4 w4 = *(const float4*)&s_wi[d * 512 + e4 * 64 + sub * 4];
        p[d] += xv[e4].x * w4.x + xv[e4].y * w4.y + xv[e4].z * w4.z + xv[e4].w * w4.w;
      }
    }
    #pragma unroll
    for (int d = 0; d < 12; ++d) {
      #pragma unroll
      for (int m = 1; m <= 8; m <<= 1) p[d] += __shfl_xor(p[d], m, 16);
      p[d] += bin[d];
    }

    unsigned idx = 0u;
    #pragma unroll
    for (int d = 0; d < 12; ++d) idx |= (p[d] > 0.f ? 1u : 0u) << (11 - d);

    // lane sub<12 writes xp[i*12+sub] (coalesced 48 B/sample); lane 12 writes index
    float v = p[0];
    #pragma unroll
    for (int d = 1; d < 12; ++d) v = (sub == d) ? p[d] : v;
    if (sub < 12)       xp[(size_t)i * 12 + sub] = v;
    else if (sub == 12) idx_out[i] = (float)idx;
  }
}

// -------- K_B: projection-out from index bits. 1 wave = 1 sample/iter,
// two contiguous 1 KB wave stores per sample. ~30 live VGPRs.
__global__ __launch_bounds__(256, 4) void k_projout(
    const float* __restrict__ idxf,
    const float* __restrict__ w_out, const float* __restrict__ b_out,
    float* __restrict__ out) {
  __shared__ __align__(16) float s_wt[6144];   // w_out^T row-major [12][512]
  const int t = threadIdx.x;
  #pragma unroll
  for (int k = 0; k < 24; ++k) {
    int f = t + k * 256;
    int d = f >> 9, e = f & 511;
    s_wt[f] = w_out[e * 12 + d];
  }
  __syncthreads();

  const int wave = t >> 6, lane = t & 63;
  const int ibase = blockIdx.x * 32 + wave * 8;
  const float4 bo0 = *(const float4*)(b_out + 4 * lane);
  const float4 bo1 = *(const float4*)(b_out + 256 + 4 * lane);

  #pragma unroll 1
  for (int s = 0; s < 8; ++s) {
    const int i = ibase + s;
    const unsigned u = (unsigned)idxf[i];   // broadcast load (L2-resident)
    float4 o0 = bo0, o1 = bo1;
    #pragma unroll
    for (int d = 0; d < 12; ++d) {
      const float sg = ((u >> (11 - d)) & 1u) ? 1.f : -1.f;
      float4 wa = *(const float4*)&s_wt[d * 512 + 4 * lane];
      float4 wb = *(const float4*)&s_wt[d * 512 + 256 + 4 * lane];
      o0.x += sg * wa.x; o0.y += sg * wa.y; o0.z += sg * wa.z; o0.w += sg * wa.w;
      o1.x += sg * wb.x; o1.y += sg * wb.y; o1.z += sg * wb.z; o1.w += sg * wb.w;
    }
    *(float4*)(out + (size_t)i * 512 + 4 * lane)       = o0;
    *(float4*)(out + (size_t)i * 512 + 256 + 4 * lane) = o1;
  }
}

// -------- K_C: factorized softmax entropy + avg_prob partials. 64 samples/block.
__global__ __launch_bounds__(512, 2) void k_entropy(
    const float* __restrict__ xp, float* __restrict__ P,
    float* __restrict__ Csum) {
  __shared__ __align__(16) float s_phi[64][64];
  __shared__ __align__(16) float s_psi[64][64];
  const int t = threadIdx.x;
  const int wave = t >> 6, lane = t & 63;
  const int ibase = blockIdx.x * 64 + wave * 8;

  float hacc = 0.f;
  #pragma unroll 1
  for (int s = 0; s < 8; ++s) {
    const int ws = wave * 8 + s;
    const float* xr = xp + (size_t)(ibase + s) * 12;   // 48 B, 16-aligned
    float4 a = *(const float4*)xr;
    float4 b = *(const float4*)(xr + 4);
    float4 c = *(const float4*)(xr + 8);
    float xq[12] = {a.x, a.y, a.z, a.w, b.x, b.y, b.z, b.w, c.x, c.y, c.z, c.w};

    float hi = 0.f, lo = 0.f, ah = 0.f, al = 0.f;
    #pragma unroll
    for (int d = 0; d < 6; ++d) {
      int bh = (lane >> (5 - d)) & 1;
      hi += bh ? xq[d]     : -xq[d];
      lo += bh ? xq[6 + d] : -xq[6 + d];
      ah += fabsf(xq[d]);
      al += fabsf(xq[6 + d]);
    }
    float lhi = INVT2 * (hi - ah);   // <= 0, lane-max == 0
    float llo = INVT2 * (lo - al);
    float ehi = __expf(lhi);
    float elo = __expf(llo);
    float Shi = ehi, Slo = elo;
    #pragma unroll
    for (int m = 1; m <= 32; m <<= 1) {
      Shi += __shfl_xor(Shi, m);
      Slo += __shfl_xor(Slo, m);
    }
    float phi = ehi / Shi;
    float psi = elo / Slo;
    float lnShi = __logf(Shi), lnSlo = __logf(Slo);
    hacc += phi * (lhi - lnShi) + psi * (llo - lnSlo);  // = -(H_hi+H_lo) part

    s_phi[ws][lane] = phi;
    s_psi[ws][lane] = psi;
  }
  #pragma unroll
  for (int m = 1; m <= 32; m <<= 1) hacc += __shfl_xor(hacc, m);
  if (lane == 0) atomicAdd(Csum, hacc);

  __syncthreads();

  // avg_prob partial P[j][l] = sum_s phi[s][j]*psi[s][l]; 4(j)x2(l) tile/thread
  const int jb = (t >> 5) * 4;
  const int lb = (t & 31) * 2;
  float a00 = 0.f, a01 = 0.f, a10 = 0.f, a11 = 0.f;
  float a20 = 0.f, a21 = 0.f, a30 = 0.f, a31 = 0.f;
  #pragma unroll 4
  for (int s = 0; s < 64; ++s) {
    float4 ph = *(const float4*)&s_phi[s][jb];
    float2 ps = *(const float2*)&s_psi[s][lb];
    a00 += ph.x * ps.x; a01 += ph.x * ps.y;
    a10 += ph.y * ps.x; a11 += ph.y * ps.y;
    a20 += ph.z * ps.x; a21 += ph.z * ps.y;
    a30 += ph.w * ps.x; a31 += ph.w * ps.y;
  }
  float* Pr = P + (size_t)blockIdx.x * 4096;
  *(float2*)&Pr[(jb + 0) * 64 + lb] = make_float2(a00, a01);
  *(float2*)&Pr[(jb + 1) * 64 + lb] = make_float2(a10, a11);
  *(float2*)&Pr[(jb + 2) * 64 + lb] = make_float2(a20, a21);
  *(float2*)&Pr[(jb + 3) * 64 + lb] = make_float2(a30, a31);
}

// -------- K2: reduce partials -> avg_prob, codebook entropy (exact, clipped)
__global__ __launch_bounds__(256) void k_reduce(const float* __restrict__ P,
                                                float* __restrict__ Esum) {
  __shared__ float red[16][17];
  __shared__ float ered[16];
  const int t = threadIdx.x;
  const int cl = t & 15, rg = t >> 4;
  const int c = blockIdx.x * 16 + cl;
  float s = 0.f;
  #pragma unroll
  for (int k = 0; k < 16; ++k) s += P[(size_t)(rg + k * 16) * 4096 + c];
  red[rg][cl] = s;
  __syncthreads();
  if (t < 16) {
    float tot = 0.f;
    #pragma unroll
    for (int r = 0; r < 16; ++r) tot += red[r][t];
    float pb = tot * (1.f / (float)NS);
    ered[t] = pb * __logf(fmaxf(pb, 1e-5f));   // p * log(clip(p, eps))
  }
  __syncthreads();
  if (t == 0) {
    float e = 0.f;
    #pragma unroll
    for (int r = 0; r < 16; ++r) e += ered[r];
    atomicAdd(Esum, e);
  }
}

// -------- K3: combine into aux_loss
__global__ void k_final(const float* __restrict__ Csum, const float* __restrict__ Esum,
                        float* __restrict__ aux) {
  if (threadIdx.x == 0) {
    float per_sample_entropy = -Csum[0] * (1.f / (float)NS);
    float codebook_entropy   = -Esum[0];
    aux[0] = 0.1f * (per_sample_entropy - codebook_entropy);
  }
}

extern "C" void kernel_launch(void* const* d_in, const int* in_sizes, int n_in,
                              void* d_out, int out_size, void* d_ws, size_t ws_size,
                              hipStream_t stream) {
  const float* x     = (const float*)d_in[0];
  const float* w_in  = (const float*)d_in[1];
  const float* b_in  = (const float*)d_in[2];
  const float* w_out = (const float*)d_in[3];
  const float* b_out = (const float*)d_in[4];
  float* out = (float*)d_out;

  float* xp   = (float*)d_ws;            // 16384*12 f32 = 768 KB
  float* P    = xp + (size_t)NS * 12;    // 256*4096 f32 = 4 MB
  float* scal = P + (size_t)256 * 4096;  // {C_sum, E_sum}

  hipMemsetAsync(scal, 0, 2 * sizeof(float), stream);
  k_projin <<<512, 256, 0, stream>>>(x, w_in, b_in, xp, out + NOUT);
  k_projout<<<512, 256, 0, stream>>>(out + NOUT, w_out, b_out, out);
  k_entropy<<<256, 512, 0, stream>>>(xp, P, scal);
  k_reduce <<<256, 256, 0, stream>>>(P, scal + 1);
  k_final  <<<1, 64, 0, stream>>>(scal, scal + 1, out + AUXO);
}

// Round 6
// 160.215 us; speedup vs baseline: 2.2268x; 2.2268x over previous
//
#include <hip/hip_runtime.h>
#include <hip/hip_bf16.h>

// LFQ forward, split into low-pressure single-purpose kernels (MI355X gfx950).
// d_out (f32): out[16384*512], indices[16384] (as float), aux_loss[1]
// ws: xp[16384*12] (768 KB) | P[256*4096] (4 MB) | scal[2] {C_sum, E_sum}
//
// NOTE: never pass a second arg to __launch_bounds__ here — empirically the
// compiler caps VGPRs at 256/arg2 (e.g. (256,4) -> 64 VGPRs) which forced
// massive scratch spill (R3/R5: 200 MB FETCH + 184 MB WRITE of pure spill).

#define NS    16384
#define NOUT  (NS*512)
#define AUXO  (NOUT+NS)
#define INVT2 200.0f

// -------- K_A: projection-in -> xp, indices. 16 lanes/sample, 32 samples/block.
__global__ __launch_bounds__(256) void k_projin(
    const float* __restrict__ x,
    const float* __restrict__ w_in, const float* __restrict__ b_in,
    float* __restrict__ xp, float* __restrict__ idx_out) {
  __shared__ __align__(16) float s_wi[6144];   // w_in row-major [12][512]
  const int t = threadIdx.x;
  #pragma unroll
  for (int k = 0; k < 24; ++k) s_wi[t + k * 256] = w_in[t + k * 256];
  __syncthreads();

  const int sub = t & 15;
  const int grp = t >> 4;   // 0..15
  float bin[12];
  #pragma unroll
  for (int d = 0; d < 12; ++d) bin[d] = b_in[d];

  #pragma unroll 1
  for (int bt = 0; bt < 2; ++bt) {
    const int i = blockIdx.x * 32 + bt * 16 + grp;
    const float* xrow = x + (size_t)i * 512;
    float4 xv[8];
    #pragma unroll
    for (int e4 = 0; e4 < 8; ++e4)
      xv[e4] = *(const float4*)(xrow + e4 * 64 + sub * 4);

    float p[12];
    #pragma unroll
    for (int d = 0; d < 12; ++d) p[d] = 0.f;
    #pragma unroll
    for (int e4 = 0; e4 < 8; ++e4) {
      #pragma unroll
      for (int d = 0; d < 12; ++d) {
        float4 w4 = *(const float4*)&s_wi[d * 512 + e4 * 64 + sub * 4];
        p[d] += xv[e4].x * w4.x + xv[e4].y * w4.y + xv[e4].z * w4.z + xv[e4].w * w4.w;
      }
    }
    #pragma unroll
    for (int d = 0; d < 12; ++d) {
      #pragma unroll
      for (int m = 1; m <= 8; m <<= 1) p[d] += __shfl_xor(p[d], m, 16);
      p[d] += bin[d];
    }

    unsigned idx = 0u;
    #pragma unroll
    for (int d = 0; d < 12; ++d) idx |= (p[d] > 0.f ? 1u : 0u) << (11 - d);

    // lane sub<12 writes xp[i*12+sub] (coalesced 48 B/sample); lane 12 writes index
    float v = p[0];
    #pragma unroll
    for (int d = 1; d < 12; ++d) v = (sub == d) ? p[d] : v;
    if (sub < 12)       xp[(size_t)i * 12 + sub] = v;
    else if (sub == 12) idx_out[i] = (float)idx;
  }
}

// -------- K_B: projection-out from index bits. 1 wave = 1 sample/iter,
// two contiguous 1 KB wave stores per sample. ~40 live VGPRs.
__global__ __launch_bounds__(256) void k_projout(
    const float* __restrict__ idxf,
    const float* __restrict__ w_out, const float* __restrict__ b_out,
    float* __restrict__ out) {
  __shared__ __align__(16) float s_wt[6144];   // w_out^T row-major [12][512]
  const int t = threadIdx.x;
  #pragma unroll
  for (int k = 0; k < 24; ++k) {
    int f = t + k * 256;
    int d = f >> 9, e = f & 511;
    s_wt[f] = w_out[e * 12 + d];
  }
  __syncthreads();

  const int wave = t >> 6, lane = t & 63;
  const int ibase = blockIdx.x * 32 + wave * 8;
  const float4 bo0 = *(const float4*)(b_out + 4 * lane);
  const float4 bo1 = *(const float4*)(b_out + 256 + 4 * lane);

  #pragma unroll 1
  for (int s = 0; s < 8; ++s) {
    const int i = ibase + s;
    const unsigned u = (unsigned)idxf[i];   // broadcast load (L2-resident)
    float4 o0 = bo0, o1 = bo1;
    #pragma unroll
    for (int d = 0; d < 12; ++d) {
      const float sg = ((u >> (11 - d)) & 1u) ? 1.f : -1.f;
      float4 wa = *(const float4*)&s_wt[d * 512 + 4 * lane];
      float4 wb = *(const float4*)&s_wt[d * 512 + 256 + 4 * lane];
      o0.x += sg * wa.x; o0.y += sg * wa.y; o0.z += sg * wa.z; o0.w += sg * wa.w;
      o1.x += sg * wb.x; o1.y += sg * wb.y; o1.z += sg * wb.z; o1.w += sg * wb.w;
    }
    *(float4*)(out + (size_t)i * 512 + 4 * lane)       = o0;
    *(float4*)(out + (size_t)i * 512 + 256 + 4 * lane) = o1;
  }
}

// -------- K_C: factorized softmax entropy + avg_prob partials. 64 samples/block.
__global__ __launch_bounds__(512) void k_entropy(
    const float* __restrict__ xp, float* __restrict__ P,
    float* __restrict__ Csum) {
  __shared__ __align__(16) float s_phi[64][64];
  __shared__ __align__(16) float s_psi[64][64];
  const int t = threadIdx.x;
  const int wave = t >> 6, lane = t & 63;
  const int ibase = blockIdx.x * 64 + wave * 8;

  float hacc = 0.f;
  #pragma unroll 1
  for (int s = 0; s < 8; ++s) {
    const int ws = wave * 8 + s;
    const float* xr = xp + (size_t)(ibase + s) * 12;   // 48 B, 16-aligned
    float4 a = *(const float4*)xr;
    float4 b = *(const float4*)(xr + 4);
    float4 c = *(const float4*)(xr + 8);
    float xq[12] = {a.x, a.y, a.z, a.w, b.x, b.y, b.z, b.w, c.x, c.y, c.z, c.w};

    float hi = 0.f, lo = 0.f, ah = 0.f, al = 0.f;
    #pragma unroll
    for (int d = 0; d < 6; ++d) {
      int bh = (lane >> (5 - d)) & 1;
      hi += bh ? xq[d]     : -xq[d];
      lo += bh ? xq[6 + d] : -xq[6 + d];
      ah += fabsf(xq[d]);
      al += fabsf(xq[6 + d]);
    }
    float lhi = INVT2 * (hi - ah);   // <= 0, lane-max == 0
    float llo = INVT2 * (lo - al);
    float ehi = __expf(lhi);
    float elo = __expf(llo);
    float Shi = ehi, Slo = elo;
    #pragma unroll
    for (int m = 1; m <= 32; m <<= 1) {
      Shi += __shfl_xor(Shi, m);
      Slo += __shfl_xor(Slo, m);
    }
    float phi = ehi / Shi;
    float psi = elo / Slo;
    float lnShi = __logf(Shi), lnSlo = __logf(Slo);
    hacc += phi * (lhi - lnShi) + psi * (llo - lnSlo);  // = -(H_hi+H_lo) part

    s_phi[ws][lane] = phi;
    s_psi[ws][lane] = psi;
  }
  #pragma unroll
  for (int m = 1; m <= 32; m <<= 1) hacc += __shfl_xor(hacc, m);
  if (lane == 0) atomicAdd(Csum, hacc);

  __syncthreads();

  // avg_prob partial P[j][l] = sum_s phi[s][j]*psi[s][l]; 4(j)x2(l) tile/thread
  const int jb = (t >> 5) * 4;
  const int lb = (t & 31) * 2;
  float a00 = 0.f, a01 = 0.f, a10 = 0.f, a11 = 0.f;
  float a20 = 0.f, a21 = 0.f, a30 = 0.f, a31 = 0.f;
  #pragma unroll 4
  for (int s = 0; s < 64; ++s) {
    float4 ph = *(const float4*)&s_phi[s][jb];
    float2 ps = *(const float2*)&s_psi[s][lb];
    a00 += ph.x * ps.x; a01 += ph.x * ps.y;
    a10 += ph.y * ps.x; a11 += ph.y * ps.y;
    a20 += ph.z * ps.x; a21 += ph.z * ps.y;
    a30 += ph.w * ps.x; a31 += ph.w * ps.y;
  }
  float* Pr = P + (size_t)blockIdx.x * 4096;
  *(float2*)&Pr[(jb + 0) * 64 + lb] = make_float2(a00, a01);
  *(float2*)&Pr[(jb + 1) * 64 + lb] = make_float2(a10, a11);
  *(float2*)&Pr[(jb + 2) * 64 + lb] = make_float2(a20, a21);
  *(float2*)&Pr[(jb + 3) * 64 + lb] = make_float2(a30, a31);
}

// -------- K2: reduce partials -> avg_prob, codebook entropy (exact, clipped)
__global__ __launch_bounds__(256) void k_reduce(const float* __restrict__ P,
                                                float* __restrict__ Esum) {
  __shared__ float red[16][17];
  __shared__ float ered[16];
  const int t = threadIdx.x;
  const int cl = t & 15, rg = t >> 4;
  const int c = blockIdx.x * 16 + cl;
  float s = 0.f;
  #pragma unroll
  for (int k = 0; k < 16; ++k) s += P[(size_t)(rg + k * 16) * 4096 + c];
  red[rg][cl] = s;
  __syncthreads();
  if (t < 16) {
    float tot = 0.f;
    #pragma unroll
    for (int r = 0; r < 16; ++r) tot += red[r][t];
    float pb = tot * (1.f / (float)NS);
    ered[t] = pb * __logf(fmaxf(pb, 1e-5f));   // p * log(clip(p, eps))
  }
  __syncthreads();
  if (t == 0) {
    float e = 0.f;
    #pragma unroll
    for (int r = 0; r < 16; ++r) e += ered[r];
    atomicAdd(Esum, e);
  }
}

// -------- K3: combine into aux_loss
__global__ void k_final(const float* __restrict__ Csum, const float* __restrict__ Esum,
                        float* __restrict__ aux) {
  if (threadIdx.x == 0) {
    float per_sample_entropy = -Csum[0] * (1.f / (float)NS);
    float codebook_entropy   = -Esum[0];
    aux[0] = 0.1f * (per_sample_entropy - codebook_entropy);
  }
}

extern "C" void kernel_launch(void* const* d_in, const int* in_sizes, int n_in,
                              void* d_out, int out_size, void* d_ws, size_t ws_size,
                              hipStream_t stream) {
  const float* x     = (const float*)d_in[0];
  const float* w_in  = (const float*)d_in[1];
  const float* b_in  = (const float*)d_in[2];
  const float* w_out = (const float*)d_in[3];
  const float* b_out = (const float*)d_in[4];
  float* out = (float*)d_out;

  float* xp   = (float*)d_ws;            // 16384*12 f32 = 768 KB
  float* P    = xp + (size_t)NS * 12;    // 256*4096 f32 = 4 MB
  float* scal = P + (size_t)256 * 4096;  // {C_sum, E_sum}

  hipMemsetAsync(scal, 0, 2 * sizeof(float), stream);
  k_projin <<<512, 256, 0, stream>>>(x, w_in, b_in, xp, out + NOUT);
  k_projout<<<512, 256, 0, stream>>>(out + NOUT, w_out, b_out, out);
  k_entropy<<<256, 512, 0, stream>>>(xp, P, scal);
  k_reduce <<<256, 256, 0, stream>>>(P, scal + 1);
  k_final  <<<1, 64, 0, stream>>>(scal, scal + 1, out + AUXO);
}

// Round 7
// 154.116 us; speedup vs baseline: 2.3149x; 1.0396x over previous
//
#include <hip/hip_runtime.h>
#include <hip/hip_bf16.h>

// LFQ forward (MI355X gfx950), spill-free split:
//   K1 k_proj    : proj-in (xp, indices) + proj-out (fused, one weight staging)
//   K2 k_entropy : factorized softmax entropy + avg_prob partials
//   K3 k_reduce  : coalesced partial reduce -> codebook entropy
//   K4 k_final   : combine scalars
// d_out (f32): out[16384*512], indices[16384] (as float), aux_loss[1]
// ws: xp[16384*12] (768 KB) | P[256*4096] (4 MB) | scal[2] {C_sum, E_sum}
//
// NOTE: never pass a second arg to __launch_bounds__ — empirically the
// compiler caps VGPRs at 256/arg2 (e.g. (256,4) -> 64 VGPRs) which forced
// massive scratch spill (R3/R5: ~200 MB FETCH + ~185 MB WRITE of pure spill).

#define NS    16384
#define NOUT  (NS*512)
#define AUXO  (NOUT+NS)
#define INVT2 200.0f

// -------- K1: fused projection-in + projection-out. 32 samples/block, 256 thr.
__global__ __launch_bounds__(256) void k_proj(
    const float* __restrict__ x,
    const float* __restrict__ w_in,  const float* __restrict__ b_in,
    const float* __restrict__ w_out, const float* __restrict__ b_out,
    float* __restrict__ out, float* __restrict__ xp, float* __restrict__ idx_out) {
  __shared__ __align__(16) float s_wi[6144];   // w_in   row-major [12][512]
  __shared__ __align__(16) float s_wt[6144];   // w_out^T row-major [12][512]
  __shared__ unsigned s_idx[32];               // per-sample sign bits
  const int t = threadIdx.x;
  #pragma unroll
  for (int k = 0; k < 24; ++k) {
    int f = t + k * 256;
    int d = f >> 9, e = f & 511;
    s_wi[f] = w_in[f];
    s_wt[f] = w_out[e * 12 + d];
  }
  __syncthreads();

  // ---- Phase A: projection-in. 16 lanes/sample, e = e4*64 + sub*4 (coalesced)
  const int sub = t & 15;
  const int grp = t >> 4;   // 0..15
  float bin[12];
  #pragma unroll
  for (int d = 0; d < 12; ++d) bin[d] = b_in[d];

  #pragma unroll 1
  for (int bt = 0; bt < 2; ++bt) {
    const int li = bt * 16 + grp;            // local sample 0..31
    const int i  = blockIdx.x * 32 + li;
    const float* xrow = x + (size_t)i * 512;
    float4 xv[8];
    #pragma unroll
    for (int e4 = 0; e4 < 8; ++e4)
      xv[e4] = *(const float4*)(xrow + e4 * 64 + sub * 4);

    float p[12];
    #pragma unroll
    for (int d = 0; d < 12; ++d) p[d] = 0.f;
    #pragma unroll
    for (int e4 = 0; e4 < 8; ++e4) {
      #pragma unroll
      for (int d = 0; d < 12; ++d) {
        float4 w4 = *(const float4*)&s_wi[d * 512 + e4 * 64 + sub * 4];
        p[d] += xv[e4].x * w4.x + xv[e4].y * w4.y + xv[e4].z * w4.z + xv[e4].w * w4.w;
      }
    }
    #pragma unroll
    for (int d = 0; d < 12; ++d) {
      #pragma unroll
      for (int m = 1; m <= 8; m <<= 1) p[d] += __shfl_xor(p[d], m, 16);
      p[d] += bin[d];
    }

    unsigned idx = 0u;
    #pragma unroll
    for (int d = 0; d < 12; ++d) idx |= (p[d] > 0.f ? 1u : 0u) << (11 - d);

    // coalesced-ish: lanes 0..11 write xp, lane 12 writes index, lane 15 -> LDS
    float v = p[0];
    #pragma unroll
    for (int d = 1; d < 12; ++d) v = (sub == d) ? p[d] : v;
    if (sub < 12)        xp[(size_t)i * 12 + sub] = v;
    else if (sub == 12)  idx_out[i] = (float)idx;
    else if (sub == 15)  s_idx[li] = idx;
  }
  __syncthreads();

  // ---- Phase B: projection-out from sign bits. 1 wave = 1 sample/iter,
  // two contiguous 1 KB wave stores per sample.
  const int wave = t >> 6, lane = t & 63;
  const float4 bo0 = *(const float4*)(b_out + 4 * lane);
  const float4 bo1 = *(const float4*)(b_out + 256 + 4 * lane);
  #pragma unroll 1
  for (int s = 0; s < 8; ++s) {
    const int li = wave * 8 + s;
    const int i  = blockIdx.x * 32 + li;
    const unsigned u = s_idx[li];   // LDS broadcast
    float4 o0 = bo0, o1 = bo1;
    #pragma unroll
    for (int d = 0; d < 12; ++d) {
      const float sg = ((u >> (11 - d)) & 1u) ? 1.f : -1.f;
      float4 wa = *(const float4*)&s_wt[d * 512 + 4 * lane];
      float4 wb = *(const float4*)&s_wt[d * 512 + 256 + 4 * lane];
      o0.x += sg * wa.x; o0.y += sg * wa.y; o0.z += sg * wa.z; o0.w += sg * wa.w;
      o1.x += sg * wb.x; o1.y += sg * wb.y; o1.z += sg * wb.z; o1.w += sg * wb.w;
    }
    *(float4*)(out + (size_t)i * 512 + 4 * lane)       = o0;
    *(float4*)(out + (size_t)i * 512 + 256 + 4 * lane) = o1;
  }
}

// -------- K2: factorized softmax entropy + avg_prob partials. 64 samples/block.
__global__ __launch_bounds__(512) void k_entropy(
    const float* __restrict__ xp, float* __restrict__ P,
    float* __restrict__ Csum) {
  __shared__ __align__(16) float s_phi[64][64];
  __shared__ __align__(16) float s_psi[64][64];
  __shared__ float s_h[8];
  const int t = threadIdx.x;
  const int wave = t >> 6, lane = t & 63;
  const int ibase = blockIdx.x * 64 + wave * 8;

  float hacc = 0.f;
  #pragma unroll 1
  for (int s = 0; s < 8; ++s) {
    const int ws = wave * 8 + s;
    const float* xr = xp + (size_t)(ibase + s) * 12;   // 48 B, 16-aligned
    float4 a = *(const float4*)xr;
    float4 b = *(const float4*)(xr + 4);
    float4 c = *(const float4*)(xr + 8);
    float xq[12] = {a.x, a.y, a.z, a.w, b.x, b.y, b.z, b.w, c.x, c.y, c.z, c.w};

    float hi = 0.f, lo = 0.f, ah = 0.f, al = 0.f;
    #pragma unroll
    for (int d = 0; d < 6; ++d) {
      int bh = (lane >> (5 - d)) & 1;
      hi += bh ? xq[d]     : -xq[d];
      lo += bh ? xq[6 + d] : -xq[6 + d];
      ah += fabsf(xq[d]);
      al += fabsf(xq[6 + d]);
    }
    float lhi = INVT2 * (hi - ah);   // <= 0, lane-max == 0
    float llo = INVT2 * (lo - al);
    float ehi = __expf(lhi);
    float elo = __expf(llo);
    float Shi = ehi, Slo = elo;
    #pragma unroll
    for (int m = 1; m <= 32; m <<= 1) {
      Shi += __shfl_xor(Shi, m);
      Slo += __shfl_xor(Slo, m);
    }
    float phi = ehi / Shi;
    float psi = elo / Slo;
    float lnShi = __logf(Shi), lnSlo = __logf(Slo);
    hacc += phi * (lhi - lnShi) + psi * (llo - lnSlo);  // = -(H_hi+H_lo) part

    s_phi[ws][lane] = phi;
    s_psi[ws][lane] = psi;
  }
  #pragma unroll
  for (int m = 1; m <= 32; m <<= 1) hacc += __shfl_xor(hacc, m);
  if (lane == 0) s_h[wave] = hacc;

  __syncthreads();   // publishes s_phi/s_psi/s_h
  if (t == 0) {
    float hs = 0.f;
    #pragma unroll
    for (int w2 = 0; w2 < 8; ++w2) hs += s_h[w2];
    atomicAdd(Csum, hs);   // 1 atomic/block (256 total)
  }

  // avg_prob partial P[j][l] = sum_s phi[s][j]*psi[s][l]; 4(j)x2(l) tile/thread
  const int jb = (t >> 5) * 4;
  const int lb = (t & 31) * 2;
  float a00 = 0.f, a01 = 0.f, a10 = 0.f, a11 = 0.f;
  float a20 = 0.f, a21 = 0.f, a30 = 0.f, a31 = 0.f;
  #pragma unroll 4
  for (int s = 0; s < 64; ++s) {
    float4 ph = *(const float4*)&s_phi[s][jb];
    float2 ps = *(const float2*)&s_psi[s][lb];
    a00 += ph.x * ps.x; a01 += ph.x * ps.y;
    a10 += ph.y * ps.x; a11 += ph.y * ps.y;
    a20 += ph.z * ps.x; a21 += ph.z * ps.y;
    a30 += ph.w * ps.x; a31 += ph.w * ps.y;
  }
  float* Pr = P + (size_t)blockIdx.x * 4096;
  *(float2*)&Pr[(jb + 0) * 64 + lb] = make_float2(a00, a01);
  *(float2*)&Pr[(jb + 1) * 64 + lb] = make_float2(a10, a11);
  *(float2*)&Pr[(jb + 2) * 64 + lb] = make_float2(a20, a21);
  *(float2*)&Pr[(jb + 3) * 64 + lb] = make_float2(a30, a31);
}

// -------- K3: reduce partials (coalesced 256 B wave reads) -> codebook entropy
__global__ __launch_bounds__(256) void k_reduce(const float* __restrict__ P,
                                                float* __restrict__ Esum) {
  __shared__ float s_red[256];
  const int t = threadIdx.x;
  const int c = blockIdx.x * 64 + (t & 63);   // code
  const int r0 = (t >> 6) * 64;               // partial-row group
  float s = 0.f;
  #pragma unroll
  for (int k = 0; k < 64; ++k) s += P[(size_t)(r0 + k) * 4096 + c];
  s_red[t] = s;
  __syncthreads();
  if (t < 64) {
    float tot = s_red[t] + s_red[64 + t] + s_red[128 + t] + s_red[192 + t];
    float pb = tot * (1.f / (float)NS);
    float e = pb * __logf(fmaxf(pb, 1e-5f));   // p * log(clip(p, eps))
    #pragma unroll
    for (int m = 1; m <= 32; m <<= 1) e += __shfl_xor(e, m);
    if (t == 0) atomicAdd(Esum, e);
  }
}

// -------- K4: combine into aux_loss
__global__ void k_final(const float* __restrict__ Csum, const float* __restrict__ Esum,
                        float* __restrict__ aux) {
  if (threadIdx.x == 0) {
    float per_sample_entropy = -Csum[0] * (1.f / (float)NS);
    float codebook_entropy   = -Esum[0];
    aux[0] = 0.1f * (per_sample_entropy - codebook_entropy);
  }
}

extern "C" void kernel_launch(void* const* d_in, const int* in_sizes, int n_in,
                              void* d_out, int out_size, void* d_ws, size_t ws_size,
                              hipStream_t stream) {
  const float* x     = (const float*)d_in[0];
  const float* w_in  = (const float*)d_in[1];
  const float* b_in  = (const float*)d_in[2];
  const float* w_out = (const float*)d_in[3];
  const float* b_out = (const float*)d_in[4];
  float* out = (float*)d_out;

  float* xp   = (float*)d_ws;            // 16384*12 f32 = 768 KB
  float* P    = xp + (size_t)NS * 12;    // 256*4096 f32 = 4 MB
  float* scal = P + (size_t)256 * 4096;  // {C_sum, E_sum}

  hipMemsetAsync(scal, 0, 2 * sizeof(float), stream);
  k_proj   <<<512, 256, 0, stream>>>(x, w_in, b_in, w_out, b_out, out, xp, out + NOUT);
  k_entropy<<<256, 512, 0, stream>>>(xp, P, scal);
  k_reduce <<<64, 256, 0, stream>>>(P, scal + 1);
  k_final  <<<1, 64, 0, stream>>>(scal, scal + 1, out + AUXO);
}